// Round 6
// baseline (118.576 us; speedup 1.0000x reference)
//
#include <hip/hip_runtime.h>
#include <math.h>

// R11: ONE element per 1024-thread block (16 waves), 4 amps/thread.
// Evidence (R7 vs R10 A/B): K tracks per-wave work ~1:1 and not issue work
// -> kernel is per-wave critical-path bound. So: HALVE per-wave work and
// DOUBLE waves/SIMD (4 -> 8).
//   flat bits [11:6] = lane (q0..q5, qubit i <-> lane bit 5-i)
//   flat bits [5:2]  = wave id (q6=8, q7=4, q8=2, q9=1)  <- LDS cross-wave
//   flat bits [1:0]  = reg (q10=bit1, q11=bit0)          <- in-register
// Per neuron now: ONE sincos pair (th[9] folds into wave-uniform wsum since
// q9 is a wave bit), one half1/half2, T on 2 values. Unitary q6..q9 merged
// into a single 16-term LDS gather (one barrier).

typedef float v2f __attribute__((ext_vector_type(2)));

__device__ __forceinline__ v2f mk(float a, float b) { v2f r; r.x = a; r.y = b; return r; }

// native sincos: v_sin_f32/v_cos_f32 take revolutions (D = sin(S0*2pi)).
__device__ __forceinline__ void fast_sincos(float a, float* s, float* c) {
    float r = a * 0.15915494309189535f;  // 1/(2*pi)
    *s = __builtin_amdgcn_sinf(r);
    *c = __builtin_amdgcn_cosf(r);
}

template <int XM>
__device__ __forceinline__ float shx(float x) {
    if constexpr (XM == 1) {        // quad_perm [1,0,3,2] = xor 1 (VALU)
        return __int_as_float(__builtin_amdgcn_update_dpp(
            0, __float_as_int(x), 0xB1, 0xF, 0xF, true));
    } else if constexpr (XM == 2) { // quad_perm [2,3,0,1] = xor 2 (VALU)
        return __int_as_float(__builtin_amdgcn_update_dpp(
            0, __float_as_int(x), 0x4E, 0xF, 0xF, true));
    } else if constexpr (XM == 8) { // row_ror:8 -> (i+8)%16 == i^8 (VALU)
        return __int_as_float(__builtin_amdgcn_update_dpp(
            0, __float_as_int(x), 0x128, 0xF, 0xF, true));
    } else if constexpr (XM == 4) { // ds_swizzle BitMode: lane' = lane ^ 4
        return __int_as_float(__builtin_amdgcn_ds_swizzle(
            __float_as_int(x), 0x101F));
    } else if constexpr (XM == 16) { // ds_swizzle BitMode: lane' = lane ^ 16
        return __int_as_float(__builtin_amdgcn_ds_swizzle(
            __float_as_int(x), 0x401F));
    } else {                         // xor 32: crosses 32-lane groups
        return __shfl_xor(x, XM, 64);
    }
}

// uncontrolled rY on a lane-bit qubit, 2 v2f of state
template <int LM>
__device__ __forceinline__ void lane_ry2(v2f (&V)[2], float c, float s, int ln) {
    float ss = (ln & LM) ? s : -s;
#pragma unroll
    for (int k = 0; k < 2; ++k) {
        v2f p = mk(shx<LM>(V[k].x), shx<LM>(V[k].y));
        V[k] = c * V[k] + ss * p;
    }
}

// merged 4-qubit cross-wave rotation R(q6)R(q7)R(q8)R(q9) (commuting):
// one full-state LDS write + ONE barrier + 16-point gather per thread.
// coeff(n,p) per bit: p=0 -> (n ? s : c), p=1 -> (n ? c : -s)   [rY]
__device__ __forceinline__ void wave_ry4(v2f (&V)[2],
                                         float c6, float s6,   // q6 (mask 8)
                                         float c7, float s7,   // q7 (mask 4)
                                         float c8, float s8,   // q8 (mask 2)
                                         float c9, float s9,   // q9 (mask 1)
                                         int wv, int ln, float4* buf) {
    const int slot = wv * 64 + ln;
    buf[slot] = make_float4(V[0].x, V[0].y, V[1].x, V[1].y);

    const float A6 = (wv & 8) ? s6 : c6,  B6 = (wv & 8) ? c6 : -s6;
    const float A7 = (wv & 4) ? s7 : c7,  B7 = (wv & 4) ? c7 : -s7;
    const float A8 = (wv & 2) ? s8 : c8,  B8 = (wv & 2) ? c8 : -s8;
    const float A9 = (wv & 1) ? s9 : c9,  B9 = (wv & 1) ? c9 : -s9;
    float khi[4], klo[4];
    khi[0] = A6 * A7; khi[1] = A6 * B7; khi[2] = B6 * A7; khi[3] = B6 * B7;
    klo[0] = A8 * A9; klo[1] = A8 * B9; klo[2] = B8 * A9; klo[3] = B8 * B9;

    __syncthreads();

    v2f a0 = mk(0.f, 0.f), a1 = a0;
#pragma unroll
    for (int hi = 0; hi < 4; ++hi) {
#pragma unroll
        for (int lo = 0; lo < 4; ++lo) {
            const float k = khi[hi] * klo[lo];
            float4 t = buf[(hi * 4 + lo) * 64 + ln];
            a0 += k * mk(t.x, t.y);
            a1 += k * mk(t.z, t.w);
        }
    }
    V[0] = a0; V[1] = a1;
}

// First half of the neuron: RB(+), crY(pi,10,11), RB(-)  on (q10,q11).
__device__ __forceinline__ void half1(v2f V0, v2f V1, float c, float s,
                                      v2f& u0, v2f& u1) {
    v2f t0 = c * V0 - s * V1;
    v2f t1 = s * V0 + c * V1;
    v2f t1s = __builtin_shufflevector(t1, t1, 1, 0);
    u0 =  c * t0 + mk(-s,  s) * t1s;
    u1 = -s * t0 + mk(-c,  c) * t1s;
}

// Second half: RB(+), crY(-pi,10,11), RB(-).
__device__ __forceinline__ void half2(v2f& V0, v2f& V1, float c, float s,
                                      v2f u0, v2f u1) {
    v2f r0 = c * u0 - s * u1;
    v2f r1 = s * u0 + c * u1;
    v2f r1s = __builtin_shufflevector(r1, r1, 1, 0);
    V0 =  c * r0 + mk( s, -s) * r1s;
    V1 = -s * r0 + mk( c, -c) * r1s;
}

// One quantum neuron, OUT = target qubit. ONE sincos pair (q9 is a wave bit).
template <int OUT>
__device__ __forceinline__ void neuron1(v2f (&V)[2], const float* __restrict__ th,
                                        int wv, int ln, float4* buf) {
    float a0 = (ln & 32) ? th[0] : 0.f;
    float a1 = (ln & 16) ? th[1] : 0.f;
    float a2 = (ln &  8) ? th[2] : 0.f;
    float a3 = (ln &  4) ? th[3] : 0.f;
    float a4 = (ln &  2) ? th[4] : 0.f;
    float a5 = (ln &  1) ? th[5] : 0.f;
    float wsum = th[10];                 // wv is wave-uniform -> SALU selects
    if (wv & 8) wsum += th[6];
    if (wv & 4) wsum += th[7];
    if (wv & 2) wsum += th[8];
    if (wv & 1) wsum += th[9];
    float phih = 0.5f * (((a0 + a1) + (a2 + a3)) + ((a4 + a5) + wsum));

    float sA, cA;
    fast_sincos(phih, &sA, &cA);

    v2f u0, u1;
    half1(V[0], V[1], cA, sA, u0, u1);

    // T = crY(pi, ctrl q11, tgt OUT) on the q11=1 (.y) components
    if constexpr (OUT < 6) {
        constexpr int LM = 1 << (5 - OUT);
        float ssn = (ln & LM) ? 1.f : -1.f;
        u0.y = ssn * shx<LM>(u0.y);
        u1.y = ssn * shx<LM>(u1.y);
    } else {  // OUT in {6,7,8,9}: wave-bit target, float2 LDS exchange
        constexpr int WM = 1 << (9 - OUT);
        float2* f2 = (float2*)buf;
        const int slot = wv * 64 + ln;
        f2[slot] = make_float2(u0.y, u1.y);
        __syncthreads();
        const int pslot = (wv ^ WM) * 64 + ln;
        float ssn = (wv & WM) ? 1.f : -1.f;
        float2 t = f2[pslot];
        u0.y = ssn * t.x; u1.y = ssn * t.y;
    }

    half2(V[0], V[1], cA, sA, u0, u1);
}

__global__ __launch_bounds__(1024, 8) void rvqe_kernel(
    const float* __restrict__ psi_in,   // (B, 4096)
    const int*   __restrict__ inp,      // (6,)
    const float* __restrict__ ut,       // (2, 10)
    const float* __restrict__ nt,       // (2, 10, 11)
    float* __restrict__ out_probs,      // (B, 64)
    float* __restrict__ out_psi)        // (B, 4096)
{
    __shared__ float4 xbuf[2][1024];  // 2 x 16 KB

    const int b   = blockIdx.x;
    const int tid = threadIdx.x;
    const int ln  = tid & 63;
    const int wv  = tid >> 6;   // 0..15: bit3=q6, bit2=q7, bit1=q8, bit0=q9
    int bi = 0;

    // BitFlip: fold X on input lanes into load address
    int flip = 0;
#pragma unroll
    for (int l = 0; l < 6; ++l)
        if (inp[l] == 1) flip |= 1 << (5 - l);

    v2f V[2];
    {
        const float* src = psi_in + (size_t)b * 4096 + (((ln ^ flip) & 63) << 6) + (wv << 2);
        float4 t0 = *(const float4*)src;
        V[0] = mk(t0.x, t0.y); V[1] = mk(t0.z, t0.w);
    }

    for (int s = 0; s < 2; ++s) {
        const float* uts = ut + s * 10;
        const float* nts = nt + (size_t)s * 110;

        // ---- UnitaryLayer: rY(uts[i]) on qubit i ----
        {
            float cc, ss;
            fast_sincos(0.5f * uts[0], &ss, &cc); lane_ry2<32>(V, cc, ss, ln);
            fast_sincos(0.5f * uts[1], &ss, &cc); lane_ry2<16>(V, cc, ss, ln);
            fast_sincos(0.5f * uts[2], &ss, &cc); lane_ry2<8>(V, cc, ss, ln);
            fast_sincos(0.5f * uts[3], &ss, &cc); lane_ry2<4>(V, cc, ss, ln);
            fast_sincos(0.5f * uts[4], &ss, &cc); lane_ry2<2>(V, cc, ss, ln);
            fast_sincos(0.5f * uts[5], &ss, &cc); lane_ry2<1>(V, cc, ss, ln);
            // qubits 6..9: ONE merged cross-wave exchange (16-term gather)
            float c6, s6, c7, s7, c8, s8, c9, s9;
            fast_sincos(0.5f * uts[6], &s6, &c6);
            fast_sincos(0.5f * uts[7], &s7, &c7);
            fast_sincos(0.5f * uts[8], &s8, &c8);
            fast_sincos(0.5f * uts[9], &s9, &c9);
            wave_ry4(V, c6, s6, c7, s7, c8, s8, c9, s9, wv, ln, xbuf[bi]); bi ^= 1;
        }

        // ---- QuantumNeuronLayer, fully unrolled (compile-time masks) ----
        neuron1<0>(V, nts + 0 * 11, wv, ln, nullptr);
        neuron1<1>(V, nts + 1 * 11, wv, ln, nullptr);
        neuron1<2>(V, nts + 2 * 11, wv, ln, nullptr);
        neuron1<3>(V, nts + 3 * 11, wv, ln, nullptr);
        neuron1<4>(V, nts + 4 * 11, wv, ln, nullptr);
        neuron1<5>(V, nts + 5 * 11, wv, ln, nullptr);
        neuron1<6>(V, nts + 6 * 11, wv, ln, xbuf[bi]); bi ^= 1;
        neuron1<7>(V, nts + 7 * 11, wv, ln, xbuf[bi]); bi ^= 1;
        neuron1<8>(V, nts + 8 * 11, wv, ln, xbuf[bi]); bi ^= 1;
        neuron1<9>(V, nts + 9 * 11, wv, ln, xbuf[bi]); bi ^= 1;
    }

    // ---- probs: marginal |amp|^2 over qubits 6..11 (wave + reg bits) ----
    float acc = V[0].x * V[0].x + V[0].y * V[0].y
              + V[1].x * V[1].x + V[1].y * V[1].y;
    {
        float* pb = (float*)&xbuf[bi][0];  // dbuf invariant: pre-barrier write ok
        pb[wv * 64 + ln] = acc;
        __syncthreads();
        if (wv == 0) {
            float t = 0.f;
#pragma unroll
            for (int w = 0; w < 16; ++w) t += pb[w * 64 + ln];
            out_probs[(size_t)b * 64 + ln] = t;
        }
    }

    // ---- write final psi ----
    float* dst = out_psi + (size_t)b * 4096 + (ln << 6) + (wv << 2);
    *(float4*)dst = make_float4(V[0].x, V[0].y, V[1].x, V[1].y);
}

extern "C" void kernel_launch(void* const* d_in, const int* in_sizes, int n_in,
                              void* d_out, int out_size, void* d_ws, size_t ws_size,
                              hipStream_t stream) {
    const float* psi = (const float*)d_in[0];
    const int*   inp = (const int*)d_in[1];
    const float* ut  = (const float*)d_in[2];
    const float* nt  = (const float*)d_in[3];

    const int B = in_sizes[0] >> 12;          // 4096 amplitudes per state
    float* probs = (float*)d_out;             // (B, 64) first
    float* opsi  = probs + (size_t)B * 64;    // then (B, 4096)

    rvqe_kernel<<<B, 1024, 0, stream>>>(psi, inp, ut, nt, probs, opsi);
}

// Round 7
// 96.877 us; speedup vs baseline: 1.2240x; 1.2240x over previous
//
#include <hip/hip_runtime.h>
#include <math.h>

// R12 = R11 with __launch_bounds__(1024, 4) instead of (1024, 8).
// R11 counters: VGPR_Count=32 (abnormally low), WRITE_SIZE=110 MB and
// FETCH=69.5 MB per dispatch (ideal: 8+8 MB), exactly deterministic ->
// scratch spill/fill traffic. The (1024,8) bound clamped the register
// allocator and spilled ~50 dwords/thread; the ~32 MB scratch working set
// thrashes L2 and the kernel runs at memory speed (60 us @ 3.1 TB/s).
// Relaxing to 4 waves/EU (VGPR budget 128) should eliminate scratch while
// keeping R11's halved per-wave critical path; if the compiler lands <=64
// VGPR, HW still co-schedules 8 waves/SIMD.
//
//   flat bits [11:6] = lane (q0..q5, qubit i <-> lane bit 5-i)
//   flat bits [5:2]  = wave id (q6=8, q7=4, q8=2, q9=1)  <- LDS cross-wave
//   flat bits [1:0]  = reg (q10=bit1, q11=bit0)          <- in-register

typedef float v2f __attribute__((ext_vector_type(2)));

__device__ __forceinline__ v2f mk(float a, float b) { v2f r; r.x = a; r.y = b; return r; }

// native sincos: v_sin_f32/v_cos_f32 take revolutions (D = sin(S0*2pi)).
__device__ __forceinline__ void fast_sincos(float a, float* s, float* c) {
    float r = a * 0.15915494309189535f;  // 1/(2*pi)
    *s = __builtin_amdgcn_sinf(r);
    *c = __builtin_amdgcn_cosf(r);
}

template <int XM>
__device__ __forceinline__ float shx(float x) {
    if constexpr (XM == 1) {        // quad_perm [1,0,3,2] = xor 1 (VALU)
        return __int_as_float(__builtin_amdgcn_update_dpp(
            0, __float_as_int(x), 0xB1, 0xF, 0xF, true));
    } else if constexpr (XM == 2) { // quad_perm [2,3,0,1] = xor 2 (VALU)
        return __int_as_float(__builtin_amdgcn_update_dpp(
            0, __float_as_int(x), 0x4E, 0xF, 0xF, true));
    } else if constexpr (XM == 8) { // row_ror:8 -> (i+8)%16 == i^8 (VALU)
        return __int_as_float(__builtin_amdgcn_update_dpp(
            0, __float_as_int(x), 0x128, 0xF, 0xF, true));
    } else if constexpr (XM == 4) { // ds_swizzle BitMode: lane' = lane ^ 4
        return __int_as_float(__builtin_amdgcn_ds_swizzle(
            __float_as_int(x), 0x101F));
    } else if constexpr (XM == 16) { // ds_swizzle BitMode: lane' = lane ^ 16
        return __int_as_float(__builtin_amdgcn_ds_swizzle(
            __float_as_int(x), 0x401F));
    } else {                         // xor 32: crosses 32-lane groups
        return __shfl_xor(x, XM, 64);
    }
}

// uncontrolled rY on a lane-bit qubit, 2 v2f of state
template <int LM>
__device__ __forceinline__ void lane_ry2(v2f (&V)[2], float c, float s, int ln) {
    float ss = (ln & LM) ? s : -s;
#pragma unroll
    for (int k = 0; k < 2; ++k) {
        v2f p = mk(shx<LM>(V[k].x), shx<LM>(V[k].y));
        V[k] = c * V[k] + ss * p;
    }
}

// merged 4-qubit cross-wave rotation R(q6)R(q7)R(q8)R(q9) (commuting):
// one full-state LDS write + ONE barrier + 16-point gather per thread.
// coeff(n,p) per bit: p=0 -> (n ? s : c), p=1 -> (n ? c : -s)   [rY]
__device__ __forceinline__ void wave_ry4(v2f (&V)[2],
                                         float c6, float s6,   // q6 (mask 8)
                                         float c7, float s7,   // q7 (mask 4)
                                         float c8, float s8,   // q8 (mask 2)
                                         float c9, float s9,   // q9 (mask 1)
                                         int wv, int ln, float4* buf) {
    const int slot = wv * 64 + ln;
    buf[slot] = make_float4(V[0].x, V[0].y, V[1].x, V[1].y);

    const float A6 = (wv & 8) ? s6 : c6,  B6 = (wv & 8) ? c6 : -s6;
    const float A7 = (wv & 4) ? s7 : c7,  B7 = (wv & 4) ? c7 : -s7;
    const float A8 = (wv & 2) ? s8 : c8,  B8 = (wv & 2) ? c8 : -s8;
    const float A9 = (wv & 1) ? s9 : c9,  B9 = (wv & 1) ? c9 : -s9;
    float khi[4], klo[4];
    khi[0] = A6 * A7; khi[1] = A6 * B7; khi[2] = B6 * A7; khi[3] = B6 * B7;
    klo[0] = A8 * A9; klo[1] = A8 * B9; klo[2] = B8 * A9; klo[3] = B8 * B9;

    __syncthreads();

    v2f a0 = mk(0.f, 0.f), a1 = a0;
#pragma unroll
    for (int hi = 0; hi < 4; ++hi) {
#pragma unroll
        for (int lo = 0; lo < 4; ++lo) {
            const float k = khi[hi] * klo[lo];
            float4 t = buf[(hi * 4 + lo) * 64 + ln];
            a0 += k * mk(t.x, t.y);
            a1 += k * mk(t.z, t.w);
        }
    }
    V[0] = a0; V[1] = a1;
}

// First half of the neuron: RB(+), crY(pi,10,11), RB(-)  on (q10,q11).
__device__ __forceinline__ void half1(v2f V0, v2f V1, float c, float s,
                                      v2f& u0, v2f& u1) {
    v2f t0 = c * V0 - s * V1;
    v2f t1 = s * V0 + c * V1;
    v2f t1s = __builtin_shufflevector(t1, t1, 1, 0);
    u0 =  c * t0 + mk(-s,  s) * t1s;
    u1 = -s * t0 + mk(-c,  c) * t1s;
}

// Second half: RB(+), crY(-pi,10,11), RB(-).
__device__ __forceinline__ void half2(v2f& V0, v2f& V1, float c, float s,
                                      v2f u0, v2f u1) {
    v2f r0 = c * u0 - s * u1;
    v2f r1 = s * u0 + c * u1;
    v2f r1s = __builtin_shufflevector(r1, r1, 1, 0);
    V0 =  c * r0 + mk( s, -s) * r1s;
    V1 = -s * r0 + mk( c, -c) * r1s;
}

// One quantum neuron, OUT = target qubit. ONE sincos pair (q9 is a wave bit).
template <int OUT>
__device__ __forceinline__ void neuron1(v2f (&V)[2], const float* __restrict__ th,
                                        int wv, int ln, float4* buf) {
    float a0 = (ln & 32) ? th[0] : 0.f;
    float a1 = (ln & 16) ? th[1] : 0.f;
    float a2 = (ln &  8) ? th[2] : 0.f;
    float a3 = (ln &  4) ? th[3] : 0.f;
    float a4 = (ln &  2) ? th[4] : 0.f;
    float a5 = (ln &  1) ? th[5] : 0.f;
    float wsum = th[10];                 // wv is wave-uniform -> SALU selects
    if (wv & 8) wsum += th[6];
    if (wv & 4) wsum += th[7];
    if (wv & 2) wsum += th[8];
    if (wv & 1) wsum += th[9];
    float phih = 0.5f * (((a0 + a1) + (a2 + a3)) + ((a4 + a5) + wsum));

    float sA, cA;
    fast_sincos(phih, &sA, &cA);

    v2f u0, u1;
    half1(V[0], V[1], cA, sA, u0, u1);

    // T = crY(pi, ctrl q11, tgt OUT) on the q11=1 (.y) components
    if constexpr (OUT < 6) {
        constexpr int LM = 1 << (5 - OUT);
        float ssn = (ln & LM) ? 1.f : -1.f;
        u0.y = ssn * shx<LM>(u0.y);
        u1.y = ssn * shx<LM>(u1.y);
    } else {  // OUT in {6,7,8,9}: wave-bit target, float2 LDS exchange
        constexpr int WM = 1 << (9 - OUT);
        float2* f2 = (float2*)buf;
        const int slot = wv * 64 + ln;
        f2[slot] = make_float2(u0.y, u1.y);
        __syncthreads();
        const int pslot = (wv ^ WM) * 64 + ln;
        float ssn = (wv & WM) ? 1.f : -1.f;
        float2 t = f2[pslot];
        u0.y = ssn * t.x; u1.y = ssn * t.y;
    }

    half2(V[0], V[1], cA, sA, u0, u1);
}

__global__ __launch_bounds__(1024, 4) void rvqe_kernel(
    const float* __restrict__ psi_in,   // (B, 4096)
    const int*   __restrict__ inp,      // (6,)
    const float* __restrict__ ut,       // (2, 10)
    const float* __restrict__ nt,       // (2, 10, 11)
    float* __restrict__ out_probs,      // (B, 64)
    float* __restrict__ out_psi)        // (B, 4096)
{
    __shared__ float4 xbuf[2][1024];  // 2 x 16 KB

    const int b   = blockIdx.x;
    const int tid = threadIdx.x;
    const int ln  = tid & 63;
    const int wv  = tid >> 6;   // 0..15: bit3=q6, bit2=q7, bit1=q8, bit0=q9
    int bi = 0;

    // BitFlip: fold X on input lanes into load address
    int flip = 0;
#pragma unroll
    for (int l = 0; l < 6; ++l)
        if (inp[l] == 1) flip |= 1 << (5 - l);

    v2f V[2];
    {
        const float* src = psi_in + (size_t)b * 4096 + (((ln ^ flip) & 63) << 6) + (wv << 2);
        float4 t0 = *(const float4*)src;
        V[0] = mk(t0.x, t0.y); V[1] = mk(t0.z, t0.w);
    }

    for (int s = 0; s < 2; ++s) {
        const float* uts = ut + s * 10;
        const float* nts = nt + (size_t)s * 110;

        // ---- UnitaryLayer: rY(uts[i]) on qubit i ----
        {
            float cc, ss;
            fast_sincos(0.5f * uts[0], &ss, &cc); lane_ry2<32>(V, cc, ss, ln);
            fast_sincos(0.5f * uts[1], &ss, &cc); lane_ry2<16>(V, cc, ss, ln);
            fast_sincos(0.5f * uts[2], &ss, &cc); lane_ry2<8>(V, cc, ss, ln);
            fast_sincos(0.5f * uts[3], &ss, &cc); lane_ry2<4>(V, cc, ss, ln);
            fast_sincos(0.5f * uts[4], &ss, &cc); lane_ry2<2>(V, cc, ss, ln);
            fast_sincos(0.5f * uts[5], &ss, &cc); lane_ry2<1>(V, cc, ss, ln);
            // qubits 6..9: ONE merged cross-wave exchange (16-term gather)
            float c6, s6, c7, s7, c8, s8, c9, s9;
            fast_sincos(0.5f * uts[6], &s6, &c6);
            fast_sincos(0.5f * uts[7], &s7, &c7);
            fast_sincos(0.5f * uts[8], &s8, &c8);
            fast_sincos(0.5f * uts[9], &s9, &c9);
            wave_ry4(V, c6, s6, c7, s7, c8, s8, c9, s9, wv, ln, xbuf[bi]); bi ^= 1;
        }

        // ---- QuantumNeuronLayer, fully unrolled (compile-time masks) ----
        neuron1<0>(V, nts + 0 * 11, wv, ln, nullptr);
        neuron1<1>(V, nts + 1 * 11, wv, ln, nullptr);
        neuron1<2>(V, nts + 2 * 11, wv, ln, nullptr);
        neuron1<3>(V, nts + 3 * 11, wv, ln, nullptr);
        neuron1<4>(V, nts + 4 * 11, wv, ln, nullptr);
        neuron1<5>(V, nts + 5 * 11, wv, ln, nullptr);
        neuron1<6>(V, nts + 6 * 11, wv, ln, xbuf[bi]); bi ^= 1;
        neuron1<7>(V, nts + 7 * 11, wv, ln, xbuf[bi]); bi ^= 1;
        neuron1<8>(V, nts + 8 * 11, wv, ln, xbuf[bi]); bi ^= 1;
        neuron1<9>(V, nts + 9 * 11, wv, ln, xbuf[bi]); bi ^= 1;
    }

    // ---- probs: marginal |amp|^2 over qubits 6..11 (wave + reg bits) ----
    float acc = V[0].x * V[0].x + V[0].y * V[0].y
              + V[1].x * V[1].x + V[1].y * V[1].y;
    {
        float* pb = (float*)&xbuf[bi][0];  // dbuf invariant: pre-barrier write ok
        pb[wv * 64 + ln] = acc;
        __syncthreads();
        if (wv == 0) {
            float t = 0.f;
#pragma unroll
            for (int w = 0; w < 16; ++w) t += pb[w * 64 + ln];
            out_probs[(size_t)b * 64 + ln] = t;
        }
    }

    // ---- write final psi ----
    float* dst = out_psi + (size_t)b * 4096 + (ln << 6) + (wv << 2);
    *(float4*)dst = make_float4(V[0].x, V[0].y, V[1].x, V[1].y);
}

extern "C" void kernel_launch(void* const* d_in, const int* in_sizes, int n_in,
                              void* d_out, int out_size, void* d_ws, size_t ws_size,
                              hipStream_t stream) {
    const float* psi = (const float*)d_in[0];
    const int*   inp = (const int*)d_in[1];
    const float* ut  = (const float*)d_in[2];
    const float* nt  = (const float*)d_in[3];

    const int B = in_sizes[0] >> 12;          // 4096 amplitudes per state
    float* probs = (float*)d_out;             // (B, 64) first
    float* opsi  = probs + (size_t)B * 64;    // then (B, 4096)

    rvqe_kernel<<<B, 1024, 0, stream>>>(psi, inp, ut, nt, probs, opsi);
}